// Round 1
// baseline (357.355 us; speedup 1.0000x reference)
//
#include <hip/hip_runtime.h>
#include <hip/hip_fp16.h>
#include <cstdint>
#include <cstddef>

#define H    50
#define TT   256      // timesteps
#define BATCH 512
#define KDIM 144      // layer-0 input dim
#define ODIM 144      // FC output dim

typedef _Float16 half8  __attribute__((ext_vector_type(8)));
typedef _Float16 half4v __attribute__((ext_vector_type(4)));
typedef float    floatx4 __attribute__((ext_vector_type(4)));
typedef int      int4v  __attribute__((ext_vector_type(4)));

__device__ __forceinline__ float rcpf(float x) { return __builtin_amdgcn_rcpf(x); }
__device__ __forceinline__ float sigm(float x) { return rcpf(1.0f + __expf(-x)); }
__device__ __forceinline__ float tanhx(float x) {
    return 1.0f - 2.0f * rcpf(__expf(2.0f * x) + 1.0f);
}

// Raw barrier: orders LDS (lgkmcnt) but leaves global loads (vmcnt) in flight.
// __syncthreads would emit s_waitcnt vmcnt(0) and drain the x-prefetch every step.
__device__ __forceinline__ void sync_lds() {
    asm volatile("s_waitcnt lgkmcnt(0)\n\ts_barrier" ::: "memory");
}
// Wave-local LDS write->read ordering (writer lane != reader lane, so the
// compiler sees no register dependency — explicit fence required).
__device__ __forceinline__ void wave_lds_fence() {
    asm volatile("s_waitcnt lgkmcnt(0)" ::: "memory");
}

// ---------- A-fragment builders (A layout: row m = lane&15, k = q*8 + j) ----------
// Row space p = kk*4 + gate (gates of one unit land in one lane's 4 C-regs).
__device__ __forceinline__ half8 make_a0(const float* __restrict__ Whh0,
                                         int kkA, int gate, int q, int s) {
    const float* r0 = Whh0 + (size_t)(gate * H + (kkA < H ? kkA : 0)) * H;
    half8 r;
    #pragma unroll
    for (int j = 0; j < 8; ++j) {
        const int k = s * 32 + q * 8 + j;
        r[j] = (_Float16)((kkA < H && k < H) ? r0[k] : 0.0f);
    }
    return r;
}
// x-projection rows: K=160 pad; k<144 = W_ih0, k==144 = bias0 (rides 1.0 B-channel)
__device__ __forceinline__ half8 make_ax(const float* __restrict__ Wih0,
                                         const float* __restrict__ bih0,
                                         const float* __restrict__ bhh0,
                                         int kkA, int gate, int q, int s) {
    const int p = gate * H + (kkA < H ? kkA : 0);
    half8 r;
    #pragma unroll
    for (int j = 0; j < 8; ++j) {
        const int k = s * 32 + q * 8 + j;
        float v = 0.0f;
        if (kkA < H) {
            if (k < KDIM)        v = Wih0[(size_t)p * KDIM + k];
            else if (k == KDIM)  v = bih0[p] + bhh0[p];
        }
        r[j] = (_Float16)v;
    }
    return r;
}
// layer-1 rows: K=128 pad; k<50 = W_ih1 (over h0), 50..99 = W_hh1 (over h1), k==100 = bias1
__device__ __forceinline__ half8 make_a1(const float* __restrict__ Wih1,
                                         const float* __restrict__ Whh1,
                                         const float* __restrict__ bih1,
                                         const float* __restrict__ bhh1,
                                         int kkA, int gate, int q, int s) {
    const int p = gate * H + (kkA < H ? kkA : 0);
    half8 r;
    #pragma unroll
    for (int j = 0; j < 8; ++j) {
        const int k = s * 32 + q * 8 + j;
        float v = 0.0f;
        if (kkA < H) {
            if (k < H)            v = Wih1[(size_t)p * H + k];
            else if (k < 2 * H)   v = Whh1[(size_t)p * H + (k - H)];
            else if (k == 100)    v = bih1[p] + bhh1[p];
        }
        r[j] = (_Float16)v;
    }
    return r;
}

// ---------- Kernel 0: pre-bake the 22 A-fragments per lstm thread ----------
// Acat[tid][22][8] f16 (180 KB, L2-resident). Order:
//   [0..3]  A0  (tl*2+s, s<2)     W_hh0
//   [4..13] Ax  (4+tl*5+s, s<5)   W_ih0 + bias0@k=144
//   [14..21]A1  (14+tl*4+s, s<4)  [W_ih1|W_hh1] + bias1@k=100
__global__ __launch_bounds__(512) void wprep(const float* __restrict__ Whh0,
                                             const float* __restrict__ Wih0,
                                             const float* __restrict__ bih0,
                                             const float* __restrict__ bhh0,
                                             const float* __restrict__ Wih1,
                                             const float* __restrict__ Whh1,
                                             const float* __restrict__ bih1,
                                             const float* __restrict__ bhh1,
                                             _Float16* __restrict__ Acat) {
    const int tid  = threadIdx.x;
    const int lane = tid & 63;
    const int w    = tid >> 6;
    const int prow = lane & 15;
    const int q    = lane >> 4;
    const int gate = prow & 3;
    const int kkA0 = 8 * w + 0 + (prow >> 2);
    const int kkA1 = 8 * w + 4 + (prow >> 2);
    half8* dst = (half8*)(Acat + (size_t)tid * 176);
    dst[0] = make_a0(Whh0, kkA0, gate, q, 0);
    dst[1] = make_a0(Whh0, kkA0, gate, q, 1);
    dst[2] = make_a0(Whh0, kkA1, gate, q, 0);
    dst[3] = make_a0(Whh0, kkA1, gate, q, 1);
    #pragma unroll
    for (int s = 0; s < 5; ++s) dst[4 + s] = make_ax(Wih0, bih0, bhh0, kkA0, gate, q, s);
    #pragma unroll
    for (int s = 0; s < 5; ++s) dst[9 + s] = make_ax(Wih0, bih0, bhh0, kkA1, gate, q, s);
    #pragma unroll
    for (int s = 0; s < 4; ++s) dst[14 + s] = make_a1(Wih1, Whh1, bih1, bhh1, kkA0, gate, q, s);
    #pragma unroll
    for (int s = 0; s < 4; ++s) dst[18 + s] = make_a1(Wih1, Whh1, bih1, bhh1, kkA1, gate, q, s);
}

// ---------- Kernel 1: fully-fused 2-layer LSTM + FC. 256 WGs x 512 thr ----------
// SINGLE raw barrier per step (double-buffered B2/XS). Gate quads stay inside the
// producing wave: col<2 lanes bounce them through a per-wave LDS scratch (no
// barrier — same-wave lgkmcnt fence), lanes 0..31 apply one activation set each
// with per-lane c-state. x(t+2) prefetched depth-2 (unroll-2 ping-pong); raw
// s_barrier leaves the loads in flight, consume waits are counted vmcnt.
__global__ __launch_bounds__(512, 1) void lstm_fused(
    const float* __restrict__ X,
    const _Float16* __restrict__ Acat,
    const float* __restrict__ Wfc, const float* __restrict__ bfc,
    float* __restrict__ out)
{
    const int b0   = blockIdx.x * 2;
    const int tid  = threadIdx.x;
    const int lane = tid & 63;
    const int w    = tid >> 6;       // wave 0..7
    const int col  = lane & 15;      // B col / C col (batch row for col<2)
    const int q    = lane >> 4;      // 0..3

    __shared__ __align__(16) _Float16 B2[2][4][4][16][8];  // h-state [buf][s][q][col][j]
    __shared__ __align__(16) float    scr[8][2][2][8][4];  // per-wave gate bounce [w][L][tl][q*2+col][gate]
    __shared__ __align__(16) _Float16 XS[2][2][160];       // x(t) [buf][row][k], 1.0@144
    __shared__ float h1f[2][52];

    // ---- load + pin the 22 pre-baked A-frags into AGPRs ----
    int4v Ap[22];
    #pragma unroll
    for (int i = 0; i < 22; ++i)
        Ap[i] = __builtin_bit_cast(int4v, *(const half8*)&Acat[(size_t)tid * 176 + i * 8]);
    #pragma unroll
    for (int i = 0; i < 22; ++i) asm volatile("" : "+a"(Ap[i]));

    // ---- activation-lane decode: lane l<32 of wave w owns unit u=8w+4tl+(idx>>1),
    //      layer L, batch row idx&1. Gate quad arrives via scr[w][L][tl][idx]. ----
    const bool act  = lane < 32;
    const int  aL   = (lane >> 4) & 1;
    const int  atl  = (lane >> 3) & 1;
    const int  aidx = lane & 7;
    const int  au   = 8 * w + 4 * atl + (aidx >> 1);
    const int  acol = aidx & 1;
    const int  ak   = aL * H + au;
    float c = 0.0f;

    const int  st     = tid - 256;           // x-stage thread (waves 4-7)
    const bool xs_act = (st >= 0 && st < 72);
    const int  xrow   = xs_act ? st / 36 : 0;
    const int  xc4    = xs_act ? st % 36 : 0;
    const float* xbase = X + ((size_t)(b0 + xrow) * TT) * KDIM + xc4 * 4;

    // ---- init: zero B2, set bias-1.0 channels, stage x(0) ----
    for (int i = tid; i < 4096; i += 512) ((int*)B2)[i] = 0;
    __syncthreads();
    if (tid < 4) {
        B2[tid >> 1][3][0][tid & 1][4] = (_Float16)1.0f;   // k=100 bias1 channel
        XS[tid >> 1][tid & 1][144]     = (_Float16)1.0f;   // k=144 bias0 channel
    }
    if (xs_act) {
        const float4 v = *(const float4*)&xbase[0];
        half4v h;
        h[0] = (_Float16)v.x; h[1] = (_Float16)v.y;
        h[2] = (_Float16)v.z; h[3] = (_Float16)v.w;
        *(half4v*)&XS[0][xrow][xc4 * 4] = h;
    }
    __syncthreads();

    // ---- prologue prefetch: x(1) ----
    float4 xl = make_float4(0.f, 0.f, 0.f, 0.f);
    if (xs_act) xl = *(const float4*)&xbase[(size_t)1 * KDIM];

    #pragma unroll 2
    for (int t = 0; t < TT; ++t) {
        #pragma unroll
        for (int i = 0; i < 22; ++i) asm volatile("" : "+a"(Ap[i]));
        const int rb = t & 1, wb = rb ^ 1;
        // phase 1: issue prefetch x(t+2); xl already holds x(t+1)
        float4 xn = make_float4(0.f, 0.f, 0.f, 0.f);
        if (xs_act && t + 2 < TT)
            xn = *(const float4*)&xbase[(size_t)(t + 2) * KDIM];
        // phase 2: LDS fragment reads (conflict-free / broadcast) + MFMA
        half8 bf[4];
        #pragma unroll
        for (int s = 0; s < 4; ++s) bf[s] = *(const half8*)&B2[rb][s][q][col][0];
        half8 xf[5];
        #pragma unroll
        for (int s = 0; s < 5; ++s) xf[s] = *(const half8*)&XS[rb][col & 1][s * 32 + q * 8];
        floatx4 a0[2], a1[2];
        #pragma unroll
        for (int tl = 0; tl < 2; ++tl) { a0[tl] = (floatx4)(0.0f); a1[tl] = (floatx4)(0.0f); }
        #pragma unroll
        for (int tl = 0; tl < 2; ++tl) {
            a0[tl] = __builtin_amdgcn_mfma_f32_16x16x32_f16(__builtin_bit_cast(half8, Ap[tl*2+0]), bf[0], a0[tl], 0, 0, 0);
            a0[tl] = __builtin_amdgcn_mfma_f32_16x16x32_f16(__builtin_bit_cast(half8, Ap[tl*2+1]), bf[1], a0[tl], 0, 0, 0);
            #pragma unroll
            for (int s = 0; s < 5; ++s)
                a0[tl] = __builtin_amdgcn_mfma_f32_16x16x32_f16(__builtin_bit_cast(half8, Ap[4+tl*5+s]), xf[s], a0[tl], 0, 0, 0);
            #pragma unroll
            for (int s = 0; s < 4; ++s)
                a1[tl] = __builtin_amdgcn_mfma_f32_16x16x32_f16(__builtin_bit_cast(half8, Ap[14+tl*4+s]), bf[s], a1[tl], 0, 0, 0);
        }
        // phase 3: wave-local gate bounce (writer lanes col<2; 8x16B, conflict-free)
        if (col < 2) {
            #pragma unroll
            for (int tl = 0; tl < 2; ++tl) {
                *(floatx4*)&scr[w][0][tl][q * 2 + col][0] = a0[tl];
                *(floatx4*)&scr[w][1][tl][q * 2 + col][0] = a1[tl];
            }
        }
        wave_lds_fence();   // same-wave write->read: lgkmcnt(0), NO barrier
        // phase 4: lane-parallel activation, per-lane c-state (L1 lags: skip at t==0)
        if (act && (aL == 0 || t > 0)) {
            const floatx4 g = *(const floatx4*)&scr[w][aL][atl][aidx][0];
            const float gi = sigm(g[0]), gf = sigm(g[1]);
            const float gg = tanhx(g[2]), go = sigm(g[3]);
            c = gf * c + gi * gg;
            const float hv = go * tanhx(c);
            if (au < H)
                B2[wb][ak >> 5][(ak >> 3) & 3][acol][ak & 7] = (_Float16)hv;
        }
        // phase 4b: stage x(t+1) into XS[wb] (counted vmcnt wait; x(t+2) stays in flight)
        if (xs_act && t + 1 < TT) {
            half4v h;
            h[0] = (_Float16)xl.x; h[1] = (_Float16)xl.y;
            h[2] = (_Float16)xl.z; h[3] = (_Float16)xl.w;
            *(half4v*)&XS[wb][xrow][xc4 * 4] = h;
        }
        xl = xn;
        // single barrier per step: B2[wb]/XS[wb] writes -> next step's reads
        sync_lds();
    }
    // ---- tail: gates1(TT-1) from B2[TT&1] = [h0(TT-1); h1(TT-2); 1.0] ----
    {
        const int rb = TT & 1;
        half8 bf[4];
        #pragma unroll
        for (int s = 0; s < 4; ++s) bf[s] = *(const half8*)&B2[rb][s][q][col][0];
        #pragma unroll
        for (int tl = 0; tl < 2; ++tl) {
            floatx4 a1 = (floatx4)(0.0f);
            #pragma unroll
            for (int s = 0; s < 4; ++s)
                a1 = __builtin_amdgcn_mfma_f32_16x16x32_f16(__builtin_bit_cast(half8, Ap[14+tl*4+s]), bf[s], a1, 0, 0, 0);
            if (col < 2)
                *(floatx4*)&scr[w][1][tl][q * 2 + col][0] = a1;
        }
        wave_lds_fence();
        if (act && aL == 1) {
            const floatx4 g = *(const floatx4*)&scr[w][1][atl][aidx][0];
            const float gi = sigm(g[0]), gf = sigm(g[1]);
            const float gg = tanhx(g[2]), go = sigm(g[3]);
            c = gf * c + gi * gg;
            if (au < H) h1f[acol][au] = go * tanhx(c);
        }
        sync_lds();
    }
    // ---- fused FC on h1(TT-1): 2 rows x 144 outs ----
    if (tid < 2 * ODIM) {
        const int r = tid / ODIM, o = tid - r * ODIM;
        float s = bfc[o];
        const float* wr = Wfc + (size_t)o * H;
        #pragma unroll
        for (int k = 0; k < H; ++k) s += wr[k] * h1f[r][k];
        out[(size_t)(b0 + r) * ODIM + o] = s;
    }
}

extern "C" void kernel_launch(void* const* d_in, const int* in_sizes, int n_in,
                              void* d_out, int out_size, void* d_ws, size_t ws_size,
                              hipStream_t stream) {
    const float* x    = (const float*)d_in[0];
    const float* wih0 = (const float*)d_in[1];
    const float* whh0 = (const float*)d_in[2];
    const float* bih0 = (const float*)d_in[3];
    const float* bhh0 = (const float*)d_in[4];
    const float* wih1 = (const float*)d_in[5];
    const float* whh1 = (const float*)d_in[6];
    const float* bih1 = (const float*)d_in[7];
    const float* bhh1 = (const float*)d_in[8];
    const float* wfc  = (const float*)d_in[9];
    const float* bfc  = (const float*)d_in[10];
    float* outp = (float*)d_out;

    _Float16* Acat = (_Float16*)d_ws;   // 512 threads x 176 halfs = 180,224 B

    wprep<<<1, 512, 0, stream>>>(whh0, wih0, bih0, bhh0, wih1, whh1, bih1, bhh1, Acat);
    lstm_fused<<<BATCH / 2, 512, 0, stream>>>(x, Acat, wfc, bfc, outp);
}

// Round 2
// 259.295 us; speedup vs baseline: 1.3782x; 1.3782x over previous
//
#include <hip/hip_runtime.h>
#include <hip/hip_fp16.h>
#include <cstdint>
#include <cstddef>

#define H    50
#define TT   256      // timesteps
#define BATCH 512
#define KDIM 144      // layer-0 input dim
#define ODIM 144      // FC output dim
#define NW   32       // windows
#define WS   8        // steps per window

typedef _Float16 half8  __attribute__((ext_vector_type(8)));
typedef _Float16 half4v __attribute__((ext_vector_type(4)));
typedef float    floatx4 __attribute__((ext_vector_type(4)));
typedef int      int4v  __attribute__((ext_vector_type(4)));

__device__ __forceinline__ float rcpf(float x) { return __builtin_amdgcn_rcpf(x); }
__device__ __forceinline__ float sigm(float x) { return rcpf(1.0f + __expf(-x)); }
__device__ __forceinline__ float tanhx(float x) {
    return 1.0f - 2.0f * rcpf(__expf(2.0f * x) + 1.0f);
}

// Raw barrier: orders LDS (lgkmcnt) but leaves global loads (vmcnt) in flight.
__device__ __forceinline__ void sync_lds() {
    asm volatile("s_waitcnt lgkmcnt(0)\n\ts_barrier" ::: "memory");
}
// Wave-local LDS write->read ordering.
__device__ __forceinline__ void wave_lds_fence() {
    asm volatile("s_waitcnt lgkmcnt(0)" ::: "memory");
}

// ---------- A-fragment builders (A layout: row m = lane&15, k = q*8 + j) ----------
__device__ __forceinline__ half8 make_a0(const float* __restrict__ Whh0,
                                         int kkA, int gate, int q, int s) {
    const float* r0 = Whh0 + (size_t)(gate * H + (kkA < H ? kkA : 0)) * H;
    half8 r;
    #pragma unroll
    for (int j = 0; j < 8; ++j) {
        const int k = s * 32 + q * 8 + j;
        r[j] = (_Float16)((kkA < H && k < H) ? r0[k] : 0.0f);
    }
    return r;
}
// x-projection rows: K=160 pad; k<144 = W_ih0, k==144 = bias0 (rides 1.0 B-channel)
__device__ __forceinline__ half8 make_ax(const float* __restrict__ Wih0,
                                         const float* __restrict__ bih0,
                                         const float* __restrict__ bhh0,
                                         int kkA, int gate, int q, int s) {
    const int p = gate * H + (kkA < H ? kkA : 0);
    half8 r;
    #pragma unroll
    for (int j = 0; j < 8; ++j) {
        const int k = s * 32 + q * 8 + j;
        float v = 0.0f;
        if (kkA < H) {
            if (k < KDIM)        v = Wih0[(size_t)p * KDIM + k];
            else if (k == KDIM)  v = bih0[p] + bhh0[p];
        }
        r[j] = (_Float16)v;
    }
    return r;
}
// layer-1 rows: K=128 pad; k<50 = W_ih1 (over h0), 50..99 = W_hh1 (over h1), k==100 = bias1
__device__ __forceinline__ half8 make_a1(const float* __restrict__ Wih1,
                                         const float* __restrict__ Whh1,
                                         const float* __restrict__ bih1,
                                         const float* __restrict__ bhh1,
                                         int kkA, int gate, int q, int s) {
    const int p = gate * H + (kkA < H ? kkA : 0);
    half8 r;
    #pragma unroll
    for (int j = 0; j < 8; ++j) {
        const int k = s * 32 + q * 8 + j;
        float v = 0.0f;
        if (kkA < H) {
            if (k < H)            v = Wih1[(size_t)p * H + k];
            else if (k < 2 * H)   v = Whh1[(size_t)p * H + (k - H)];
            else if (k == 100)    v = bih1[p] + bhh1[p];
        }
        r[j] = (_Float16)v;
    }
    return r;
}

// ---------- Kernel 0: pre-bake A-fragments. PARALLEL: 22 blocks x 512 thr ----------
// Block f computes fragment f for every lstm thread tid (was 1 serial block = ~115us).
__global__ __launch_bounds__(512) void wprep(const float* __restrict__ Whh0,
                                             const float* __restrict__ Wih0,
                                             const float* __restrict__ bih0,
                                             const float* __restrict__ bhh0,
                                             const float* __restrict__ Wih1,
                                             const float* __restrict__ Whh1,
                                             const float* __restrict__ bih1,
                                             const float* __restrict__ bhh1,
                                             _Float16* __restrict__ Acat) {
    const int tid  = threadIdx.x;
    const int f    = blockIdx.x;     // fragment index 0..21
    const int lane = tid & 63;
    const int w    = tid >> 6;
    const int prow = lane & 15;
    const int q    = lane >> 4;
    const int gate = prow & 3;
    const int kkA0 = 8 * w + 0 + (prow >> 2);
    const int kkA1 = 8 * w + 4 + (prow >> 2);
    half8 v;
    if      (f < 2)  v = make_a0(Whh0, kkA0, gate, q, f);
    else if (f < 4)  v = make_a0(Whh0, kkA1, gate, q, f - 2);
    else if (f < 9)  v = make_ax(Wih0, bih0, bhh0, kkA0, gate, q, f - 4);
    else if (f < 14) v = make_ax(Wih0, bih0, bhh0, kkA1, gate, q, f - 9);
    else if (f < 18) v = make_a1(Wih1, Whh1, bih1, bhh1, kkA0, gate, q, f - 14);
    else             v = make_a1(Wih1, Whh1, bih1, bhh1, kkA1, gate, q, f - 18);
    *(half8*)&Acat[(size_t)tid * 176 + f * 8] = v;
}

// ---------- Kernel 1: fused 2-layer LSTM + FC. 256 WGs x 512 thr ----------
// x-projection batched 8 timesteps/window: one MFMA pass over XB (16 cols = 8t x 2rows)
// fills wave-private gp[u][t][r] gate-quads; the serial recurrence only does the
// hh MFMAs (2 for L0, 4 for L1 per tile). One raw s_barrier per step. x loaded
// once per window (issue at window start, LDS-write at step 3 -> no vmcnt stall).
__global__ __launch_bounds__(512, 1) void lstm_fused(
    const float* __restrict__ X,
    const _Float16* __restrict__ Acat,
    const float* __restrict__ Wfc, const float* __restrict__ bfc,
    float* __restrict__ out)
{
    const int b0   = blockIdx.x * 2;
    const int tid  = threadIdx.x;
    const int lane = tid & 63;
    const int w    = tid >> 6;       // wave 0..7
    const int col  = lane & 15;      // B col / C col
    const int q    = lane >> 4;      // 0..3

    __shared__ __align__(16) _Float16 B2[2][4][4][16][8];   // h-state [buf][s][q][col][j]
    __shared__ __align__(16) float    scr[8][2][2][8][4];   // per-wave gate bounce
    __shared__ __align__(16) float    gp[64 * 72];          // xproj quads [u][t*8+r*4+g], 72-word stride
    __shared__ __align__(16) _Float16 XB[2][5][4][16][8];   // x B-frags [buf][s][q][c][j], c=2t+r
    __shared__ float h1f[2][52];

    // ---- load + pin the 22 pre-baked A-frags into AGPRs ----
    int4v Ap[22];
    #pragma unroll
    for (int i = 0; i < 22; ++i)
        Ap[i] = __builtin_bit_cast(int4v, *(const half8*)&Acat[(size_t)tid * 176 + i * 8]);
    #pragma unroll
    for (int i = 0; i < 22; ++i) asm volatile("" : "+a"(Ap[i]));

    // ---- activation-lane decode ----
    const bool act  = lane < 32;
    const int  aL   = (lane >> 4) & 1;
    const int  atl  = (lane >> 3) & 1;
    const int  aidx = lane & 7;
    const int  au   = 8 * w + 4 * atl + (aidx >> 1);
    const int  acol = aidx & 1;
    const int  ak   = aL * H + au;
    float c = 0.0f;

    // ---- x-stage decode: 576 float4/window over 512(+64) threads ----
    const int cs1 = tid / 36,         kk1 = tid % 36;
    const int cs2 = (tid + 512) / 36, kk2 = (tid + 512) % 36;
    const float* xp1 = X + ((size_t)(b0 + (cs1 & 1)) * TT + (cs1 >> 1)) * KDIM + kk1 * 4;
    const float* xp2 = X + ((size_t)(b0 + (cs2 & 1)) * TT + (cs2 >> 1)) * KDIM + kk2 * 4;

    // ---- init: zero B2 + XB, set bias-1.0 channels, stage XB[0] (tokens 0..7) ----
    for (int i = tid; i < 2048; i += 512) ((int*)B2)[i] = 0;
    for (int i = tid; i < 2560; i += 512) ((int*)XB)[i] = 0;
    __syncthreads();
    if (tid < 4)  B2[tid >> 1][3][0][tid & 1][4]  = (_Float16)1.0f;  // k=100 bias1
    if (tid < 32) XB[tid >> 4][4][2][tid & 15][0] = (_Float16)1.0f;  // k=144 bias0
    {
        const float4 v1 = *(const float4*)xp1;
        const int s = kk1 >> 3, qq = (kk1 >> 1) & 3, j0 = (kk1 & 1) * 4;
        half4v h; h[0]=(_Float16)v1.x; h[1]=(_Float16)v1.y; h[2]=(_Float16)v1.z; h[3]=(_Float16)v1.w;
        *(half4v*)&XB[0][s][qq][cs1][j0] = h;
        if (tid < 64) {
            const float4 v2 = *(const float4*)xp2;
            const int s2 = kk2 >> 3, q2 = (kk2 >> 1) & 3, j2 = (kk2 & 1) * 4;
            half4v h2; h2[0]=(_Float16)v2.x; h2[1]=(_Float16)v2.y; h2[2]=(_Float16)v2.z; h2[3]=(_Float16)v2.w;
            *(half4v*)&XB[0][s2][q2][cs2][j2] = h2;
        }
    }
    __syncthreads();

    for (int W = 0; W < NW; ++W) {
        #pragma unroll
        for (int i = 0; i < 22; ++i) asm volatile("" : "+a"(Ap[i]));
        const int cb = W & 1, nb = cb ^ 1;
        const bool more = (W + 1) < NW;
        // issue next-window x loads (consumed at step 3 -> latency hidden)
        float4 xv1, xv2;
        if (more) {
            xv1 = *(const float4*)(xp1 + (size_t)(W + 1) * WS * KDIM);
            if (tid < 64) xv2 = *(const float4*)(xp2 + (size_t)(W + 1) * WS * KDIM);
        }
        // ---- proj phase: xproj+bias0 for 16 tokens, full 16-col MFMA efficiency ----
        {
            half8 xbf[5];
            #pragma unroll
            for (int s = 0; s < 5; ++s) xbf[s] = *(const half8*)&XB[cb][s][q][col][0];
            floatx4 px0 = (floatx4)(0.0f), px1 = (floatx4)(0.0f);
            #pragma unroll
            for (int s = 0; s < 5; ++s) {
                px0 = __builtin_amdgcn_mfma_f32_16x16x32_f16(__builtin_bit_cast(half8, Ap[4 + s]), xbf[s], px0, 0, 0, 0);
                px1 = __builtin_amdgcn_mfma_f32_16x16x32_f16(__builtin_bit_cast(half8, Ap[9 + s]), xbf[s], px1, 0, 0, 0);
            }
            // wave-private scatter: lane(c,q) reg g -> token c, unit 8w+4tl+q, gate g
            const int gb = (col >> 1) * 8 + (col & 1) * 4;
            *(floatx4*)&gp[(8 * w + q) * 72 + gb]     = px0;
            *(floatx4*)&gp[(8 * w + 4 + q) * 72 + gb] = px1;
        }
        // ---- 8 recurrent steps ----
        #pragma unroll
        for (int i = 0; i < WS; ++i) {
            const int rb = i & 1, wb = rb ^ 1;
            half8 bf[4];
            #pragma unroll
            for (int s = 0; s < 4; ++s) bf[s] = *(const half8*)&B2[rb][s][q][col][0];
            floatx4 a0[2], a1[2];
            #pragma unroll
            for (int tl = 0; tl < 2; ++tl) { a0[tl] = (floatx4)(0.0f); a1[tl] = (floatx4)(0.0f); }
            #pragma unroll
            for (int tl = 0; tl < 2; ++tl) {
                a0[tl] = __builtin_amdgcn_mfma_f32_16x16x32_f16(__builtin_bit_cast(half8, Ap[tl*2+0]), bf[0], a0[tl], 0, 0, 0);
                a0[tl] = __builtin_amdgcn_mfma_f32_16x16x32_f16(__builtin_bit_cast(half8, Ap[tl*2+1]), bf[1], a0[tl], 0, 0, 0);
                #pragma unroll
                for (int s = 0; s < 4; ++s)
                    a1[tl] = __builtin_amdgcn_mfma_f32_16x16x32_f16(__builtin_bit_cast(half8, Ap[14+tl*4+s]), bf[s], a1[tl], 0, 0, 0);
            }
            if (col < 2) {
                #pragma unroll
                for (int tl = 0; tl < 2; ++tl) {
                    *(floatx4*)&scr[w][0][tl][q * 2 + col][0] = a0[tl];
                    *(floatx4*)&scr[w][1][tl][q * 2 + col][0] = a1[tl];
                }
            }
            wave_lds_fence();   // same-wave scr+gp write->read, NO barrier
            if (act && (aL == 0 || W > 0 || i > 0)) {
                floatx4 g = *(const floatx4*)&scr[w][aL][atl][aidx][0];
                if (aL == 0) {
                    const floatx4 gx = *(const floatx4*)&gp[au * 72 + i * 8 + acol * 4];
                    g[0] += gx[0]; g[1] += gx[1]; g[2] += gx[2]; g[3] += gx[3];
                }
                const float gi = sigm(g[0]), gf = sigm(g[1]);
                const float gg = tanhx(g[2]), go = sigm(g[3]);
                c = gf * c + gi * gg;
                const float hv = go * tanhx(c);
                if (au < H)
                    B2[wb][ak >> 5][(ak >> 3) & 3][acol][ak & 7] = (_Float16)hv;
            }
            // mid-window: write next-window x into XB[nb] (loads long in flight)
            if (i == 3 && more) {
                {
                    const int s = kk1 >> 3, qq = (kk1 >> 1) & 3, j0 = (kk1 & 1) * 4;
                    half4v h; h[0]=(_Float16)xv1.x; h[1]=(_Float16)xv1.y; h[2]=(_Float16)xv1.z; h[3]=(_Float16)xv1.w;
                    *(half4v*)&XB[nb][s][qq][cs1][j0] = h;
                }
                if (tid < 64) {
                    const int s2 = kk2 >> 3, q2 = (kk2 >> 1) & 3, j2 = (kk2 & 1) * 4;
                    half4v h2; h2[0]=(_Float16)xv2.x; h2[1]=(_Float16)xv2.y; h2[2]=(_Float16)xv2.z; h2[3]=(_Float16)xv2.w;
                    *(half4v*)&XB[nb][s2][q2][cs2][j2] = h2;
                }
            }
            sync_lds();         // B2[wb]/XB[nb] -> next step
        }
    }
    // ---- tail: gates1(TT-1) from B2[0] = [h0(TT-1); h1(TT-2); 1.0] ----
    {
        half8 bf[4];
        #pragma unroll
        for (int s = 0; s < 4; ++s) bf[s] = *(const half8*)&B2[0][s][q][col][0];
        #pragma unroll
        for (int tl = 0; tl < 2; ++tl) {
            floatx4 a1 = (floatx4)(0.0f);
            #pragma unroll
            for (int s = 0; s < 4; ++s)
                a1 = __builtin_amdgcn_mfma_f32_16x16x32_f16(__builtin_bit_cast(half8, Ap[14+tl*4+s]), bf[s], a1, 0, 0, 0);
            if (col < 2)
                *(floatx4*)&scr[w][1][tl][q * 2 + col][0] = a1;
        }
        wave_lds_fence();
        if (act && aL == 1) {
            const floatx4 g = *(const floatx4*)&scr[w][1][atl][aidx][0];
            const float gi = sigm(g[0]), gf = sigm(g[1]);
            const float gg = tanhx(g[2]), go = sigm(g[3]);
            c = gf * c + gi * gg;
            if (au < H) h1f[acol][au] = go * tanhx(c);
        }
        sync_lds();
    }
    // ---- fused FC on h1(TT-1): 2 rows x 144 outs ----
    if (tid < 2 * ODIM) {
        const int r = tid / ODIM, o = tid - r * ODIM;
        float s = bfc[o];
        const float* wr = Wfc + (size_t)o * H;
        #pragma unroll
        for (int k = 0; k < H; ++k) s += wr[k] * h1f[r][k];
        out[(size_t)(b0 + r) * ODIM + o] = s;
    }
}

extern "C" void kernel_launch(void* const* d_in, const int* in_sizes, int n_in,
                              void* d_out, int out_size, void* d_ws, size_t ws_size,
                              hipStream_t stream) {
    const float* x    = (const float*)d_in[0];
    const float* wih0 = (const float*)d_in[1];
    const float* whh0 = (const float*)d_in[2];
    const float* bih0 = (const float*)d_in[3];
    const float* bhh0 = (const float*)d_in[4];
    const float* wih1 = (const float*)d_in[5];
    const float* whh1 = (const float*)d_in[6];
    const float* bih1 = (const float*)d_in[7];
    const float* bhh1 = (const float*)d_in[8];
    const float* wfc  = (const float*)d_in[9];
    const float* bfc  = (const float*)d_in[10];
    float* outp = (float*)d_out;

    _Float16* Acat = (_Float16*)d_ws;   // 512 threads x 176 halfs = 180,224 B

    wprep<<<22, 512, 0, stream>>>(whh0, wih0, bih0, bhh0, wih1, whh1, bih1, bhh1, Acat);
    lstm_fused<<<BATCH / 2, 512, 0, stream>>>(x, Acat, wfc, bfc, outp);
}